// Round 8
// baseline (141.205 us; speedup 1.0000x reference)
//
#include <hip/hip_runtime.h>
#include <hip/hip_bf16.h>
#include <stdint.h>

// ZoeDepth attractor head, R9: R7 asm-pipeline + R8 VALU cuts, register-safe.
// R8 post-mortem: launch_bounds(256,4) cap=128 < pinned liveness ~145 =>
// allocator spilled volatile-asm load DESTINATIONS (compiler treats asm as
// synchronous; spill store can run before data returns; hw writeback then
// corrupts a reassigned register) => device fault. R9 cuts demand to ~110:
// SINGLE-buffer af[8] (32 regs, not 64), MFMAs pinned above next-loads by
// sched_barrier(0) so af live ranges don't overlap. New in-order vmcnt
// ledger {16,8,8,8,8,8,0,0}: AF distance-1 (L2), X distance-3 (HBM).
// Keeps: v_cvt_pk_bf16_f32 pack, float2 pk-attractor, v_exp_f32 w/ folded
// -alpha*log2(e), saddr-form asm loads, launch_bounds(256,4) one round.

#define HW 16384
#define ALPHA 300.0f
#define EXP2K -432.8085122666891f  // -ALPHA * log2(e)

typedef short bf16x8_t __attribute__((ext_vector_type(8)));
typedef float f32x4_t __attribute__((ext_vector_type(4)));
typedef float f32x2_t __attribute__((ext_vector_type(2)));
typedef unsigned int u32x4_t __attribute__((ext_vector_type(4)));

__device__ __forceinline__ unsigned short f2bf(float f) {
  unsigned int u = __builtin_bit_cast(unsigned int, f);
  u += 0x7fffu + ((u >> 16) & 1u);
  return (unsigned short)(u >> 16);
}
// hardware packed f32->bf16 (RNE), one VALU op for two elements
__device__ __forceinline__ unsigned int cvtpk(float lo, float hi) {
  unsigned int r;
  asm("v_cvt_pk_bf16_f32 %0, %1, %2" : "=v"(r) : "v"(lo), "v"(hi));
  return r;
}
// 2^x (arg already in log2 domain)
__device__ __forceinline__ float exp2a(float x) {
  float r;
  asm("v_exp_f32 %0, %1" : "=v"(r) : "v"(x));
  return r;
}
// volatile-asm loads: program-order issue; 32-bit voffset + SGPR base
__device__ __forceinline__ float aldo(unsigned int voff, const void* sbase) {
  float r;
  asm volatile("global_load_dword %0, %1, %2" : "=v"(r) : "v"(voff), "s"(sbase));
  return r;
}
__device__ __forceinline__ u32x4_t ald4o(unsigned int voff, const void* sbase) {
  u32x4_t r;
  asm volatile("global_load_dwordx4 %0, %1, %2" : "=v"(r) : "v"(voff), "s"(sbase));
  return r;
}

// ---------------------------------------------------------------------------
// Prep: w1 (128x256) and w2 (16x128) fp32 -> bf16 blobs in frag layout,
// 16B granules XOR-swizzled by (row&3). w1: 8 chunks x 8192 B @0.
// w2: 4 chunks x 1024 B @byte 65536.  (unchanged, verified)
// ---------------------------------------------------------------------------
__global__ void zoed_prep(const float* __restrict__ w1,
                          const float* __restrict__ w2,
                          unsigned short* __restrict__ blob) {
  int i = blockIdx.x * 256 + threadIdx.x;  // 136*256 = 34816 = 32768 + 2048
  if (i < 32768) {
    int o = i >> 8, c = i & 255;
    float v = w1[i];
    int idx = (c >> 5) * 4096 + o * 32 + ((((c >> 3) & 3) ^ (o & 3)) << 3) + (c & 7);
    blob[idx] = f2bf(v);
  } else {
    int i2 = i - 32768;
    int a = i2 >> 7, o = i2 & 127;
    float v = w2[i2];
    int idx = 32768 + (o >> 5) * 512 + a * 32 + ((((o >> 3) & 3) ^ (a & 3)) << 3) + (o & 7);
    blob[idx] = f2bf(v);
  }
}

// One pipelined K-iteration, single-buffer af. Order:
//   s_waitcnt vmcnt(NWAIT)   (completes AF(kb)+X(kb); queue derived below)
//   sched_barrier(0)         (rule 18: fence register-only consumers)
//   pack X(kb) + 8 MFMA      (consume af)
//   sched_barrier(0)         (pin MFMAs ABOVE next loads -> af ranges
//                             disjoint -> allocator reuses = single buffer)
//   issue AF(kb+1) [8x dwordx4], then X(kb+3) [8x dword]
// Queue evolution (in-order vmcnt): [AF0,X0,X1,X2] ->(it0 w16)-> [X1,X2]
// +AF1,X3 ->(w8)-> [X3] +AF2,X4 ->(w8)-> ... steady w8; tail w0,w0.
#define KITER(KB, NWAIT, AFNEXT, XNEXT)                                     \
  {                                                                         \
    constexpr int kb = KB;                                                  \
    asm volatile("s_waitcnt vmcnt(" #NWAIT ")");                            \
    __builtin_amdgcn_sched_barrier(0);                                      \
    u32x4_t v = {cvtpk(xr[kb & 3][0], xr[kb & 3][1]),                       \
                 cvtpk(xr[kb & 3][2], xr[kb & 3][3]),                       \
                 cvtpk(xr[kb & 3][4], xr[kb & 3][5]),                       \
                 cvtpk(xr[kb & 3][6], xr[kb & 3][7])};                      \
    bf16x8_t bfm = __builtin_bit_cast(bf16x8_t, v);                         \
    _Pragma("unroll") for (int tm = 0; tm < 8; tm++)                        \
        acc[tm] = __builtin_amdgcn_mfma_f32_16x16x32_bf16(                  \
            __builtin_bit_cast(bf16x8_t, af[tm]), bfm, acc[tm], 0, 0, 0);   \
    __builtin_amdgcn_sched_barrier(0);                                      \
    if (AFNEXT) {                                                           \
      _Pragma("unroll") for (int tm = 0; tm < 8; tm++)                      \
          af[tm] =                                                          \
              ald4o(voffw + (unsigned)((kb + 1) * 8192 + tm * 1024), wblob);\
    }                                                                       \
    if (XNEXT) {                                                            \
      _Pragma("unroll") for (int j = 0; j < 8; j++)                         \
          xr[(kb + 3) & 3][j] =                                             \
              aldo(voffx + (unsigned)(((kb + 3) * 32 + j) * HW) * 4u, xs);  \
    }                                                                       \
  }

// ---------------------------------------------------------------------------
// Fused, barrier-free, asm-pipelined. Grid: 1024 blocks x 256 thr,
// 4 blocks/CU resident (one round). Each of the 4 waves owns px [p0, p0+16).
// LDS: hid 4x4096 @0, Abuf 4x1280 @16384.
// ---------------------------------------------------------------------------
__global__ __launch_bounds__(256, 4) void zoed_fused(
    const float* __restrict__ x, const float* __restrict__ bprev,
    const float* __restrict__ b1, const float* __restrict__ b2,
    const unsigned short* __restrict__ wblob, float* __restrict__ out) {
  __shared__ __align__(16) char smem[21504];

  const int t = threadIdx.x;
  const int lane = t & 63;
  const int l15 = lane & 15;
  const int quad = lane >> 4;
  const int wv = t >> 6;
  const int sw = ((quad ^ (l15 & 3)) << 4);

  const int blk = blockIdx.x;
  const int n = blk >> 8;
  const int p0 = ((blk & 255) << 6) + wv * 16;  // this wave's 16-px base

  char* hid = smem + wv * 4096;          // 16px x 128o bf16, frag layout
  char* Ab = smem + 16384 + wv * 1280;   // 16px x 16attr f32, 80B rows

  // x addressing: SGPR base = x + n*256*HW; 32-bit byte voffset per lane.
  const float* xs = x + (size_t)(n * 256) * HW;
  const unsigned voffx = (unsigned)((quad * 8) * HW + p0 + l15) * 4u;
  const unsigned voffw = (unsigned)(l15 * 64 + sw);

  // ---- prologue (issue order fixed by volatile asm):
  // AF0 [8 dwordx4], X0 X1 X2 [24 dword] -> 32 outstanding ----
  u32x4_t af[8];
#pragma unroll
  for (int tm = 0; tm < 8; tm++) af[tm] = ald4o(voffw + tm * 1024, wblob);
  float xr[4][8];
#pragma unroll
  for (int c = 0; c < 3; c++)
#pragma unroll
    for (int j = 0; j < 8; j++)
      xr[c][j] = aldo(voffx + (unsigned)((c * 32 + j) * HW) * 4u, xs);

  f32x4_t acc[8];
#pragma unroll
  for (int i = 0; i < 8; i++) acc[i] = (f32x4_t){0.f, 0.f, 0.f, 0.f};

  // Ledger (queue before wait -> NWAIT so AF(kb)+X(kb) complete):
  KITER(0, 16, 1, 1)  // [AF0,X0,X1,X2] -> w16; +AF1,X3
  KITER(1, 8, 1, 1)   // [X1,X2,AF1,X3] -> w8;  +AF2,X4
  KITER(2, 8, 1, 1)   // [X3,AF2,X4]    -> w8;  +AF3,X5
  KITER(3, 8, 1, 1)   // [X4,AF3,X5]    -> w8;  +AF4,X6
  KITER(4, 8, 1, 1)   // [X5,AF4,X6]    -> w8;  +AF5,X7
  KITER(5, 8, 1, 0)   // [X6,AF5,X7]    -> w8;  +AF6
  KITER(6, 0, 1, 0)   // [X7,AF6]       -> w0;  +AF7
  KITER(7, 0, 0, 0)   // [AF7]          -> w0
  // queue drained (vmcnt 0): compiler-generated loads are safe from here on

  // ---- post-loop loads: bprev (16) + w2 frags (4); latency hides under
  // the epilogue VALU work ----
  size_t obase = (size_t)(n * 64 + quad * 16) * HW + p0 + l15;
  const float* bp = bprev + obase;
  float bpr[16];
#pragma unroll
  for (int b = 0; b < 16; b++) bpr[b] = bp[(size_t)b * HW];
  bf16x8_t a2[4];
#pragma unroll
  for (int kc = 0; kc < 4; kc++)
    a2[kc] = *(const bf16x8_t*)((const char*)wblob + 65536 + kc * 1024 +
                                l15 * 64 + sw);

  // ---- hidden epilogue: relu(acc + b1) -> bf16 -> hid (wave-local) ----
#pragma unroll
  for (int tm = 0; tm < 8; tm++) {
    f32x4_t b1v = *(const f32x4_t*)(b1 + tm * 16 + quad * 4);
    f32x4_t h = acc[tm] + b1v;
    h[0] = fmaxf(h[0], 0.f);
    h[1] = fmaxf(h[1], 0.f);
    h[2] = fmaxf(h[2], 0.f);
    h[3] = fmaxf(h[3], 0.f);
    int kc = tm >> 1;
    int g = (tm & 1) * 2 + (quad >> 1);
    int off8 = (quad & 1) * 8;
    unsigned int* dst = (unsigned int*)(hid + kc * 1024 + l15 * 64 +
                                        ((g ^ (l15 & 3)) << 4) + off8);
    dst[0] = cvtpk(h[0], h[1]);
    dst[1] = cvtpk(h[2], h[3]);
  }
  // ---- GEMM2: A(16attr x 16px) = softplus(w2 @ hidden + b2) ----
  // same-wave LDS write->read: lgkmcnt ordering only, no barrier
  f32x4_t acc2 = (f32x4_t){0.f, 0.f, 0.f, 0.f};
#pragma unroll
  for (int kc = 0; kc < 4; kc++) {
    bf16x8_t bh = *(const bf16x8_t*)(hid + kc * 1024 + l15 * 64 + sw);
    acc2 = __builtin_amdgcn_mfma_f32_16x16x32_bf16(a2[kc], bh, acc2, 0, 0, 0);
  }
  {
    f32x4_t b2v = *(const f32x4_t*)(b2 + quad * 4);
    f32x4_t z = acc2 + b2v;
    f32x4_t spv;
#pragma unroll
    for (int r = 0; r < 4; r++) {
      float zz = z[r];
      spv[r] = fmaxf(zz, 0.f) + log1pf(__expf(-fabsf(zz)));  // stable softplus
    }
    // A[attr quad*4+r][px l15] -> Abuf row px (80B stride breaks bank aliasing)
    *(f32x4_t*)(Ab + l15 * 80 + quad * 16) = spv;
  }
  // ---- redistribute: each lane grabs all 16 A of its px, as f32x2 pairs ----
  f32x2_t av2[8];
#pragma unroll
  for (int q = 0; q < 4; q++) {
    f32x4_t v = *(const f32x4_t*)(Ab + l15 * 80 + q * 16);
    av2[q * 2] = (f32x2_t){v[0], v[1]};
    av2[q * 2 + 1] = (f32x2_t){v[2], v[3]};
  }
  // ---- attractor: lane = (px=l15, bin-group=quad), 16 bins/lane.
  // Attractor-pairs as float2 -> v_pk_{add,mul,fma}_f32; exp2 with folded
  // -alpha*log2(e); two independent fma chains per bin. ----
  const f32x2_t K2 = {EXP2K, EXP2K};
  float* o1 = out + obase;
  float* o2 = o1 + (size_t)256 * HW;
#pragma unroll
  for (int b = 0; b < 16; b++) {
    float c = bpr[b];
    f32x2_t c2 = {c, c};
    f32x2_t d0 = {0.f, 0.f}, d1 = {0.f, 0.f};
#pragma unroll
    for (int k = 0; k < 4; k++) {
      f32x2_t dx = av2[k] - c2;
      f32x2_t tt = dx * K2;
      f32x2_t arg = tt * dx;
      f32x2_t e = {exp2a(arg[0]), exp2a(arg[1])};
      d0 = e * dx + d0;
    }
#pragma unroll
    for (int k = 4; k < 8; k++) {
      f32x2_t dx = av2[k] - c2;
      f32x2_t tt = dx * K2;
      f32x2_t arg = tt * dx;
      f32x2_t e = {exp2a(arg[0]), exp2a(arg[1])};
      d1 = e * dx + d1;
    }
    f32x2_t ds = d0 + d1;
    float r = c + (ds[0] + ds[1]);
    __builtin_nontemporal_store(r, o1 + (size_t)b * HW);
    __builtin_nontemporal_store(r, o2 + (size_t)b * HW);
  }
}

extern "C" void kernel_launch(void* const* d_in, const int* in_sizes, int n_in,
                              void* d_out, int out_size, void* d_ws,
                              size_t ws_size, hipStream_t stream) {
  const float* x = (const float*)d_in[0];      // 4*256*128*128
  const float* bprev = (const float*)d_in[1];  // 4*64*128*128
  const float* w1 = (const float*)d_in[2];     // 128*256
  const float* b1 = (const float*)d_in[3];     // 128
  const float* w2 = (const float*)d_in[4];     // 16*128
  const float* b2 = (const float*)d_in[5];     // 16
  float* outp = (float*)d_out;                 // 2 * 4194304
  unsigned short* blob = (unsigned short*)d_ws;  // 69632 B used

  zoed_prep<<<136, 256, 0, stream>>>(w1, w2, blob);
  zoed_fused<<<1024, 256, 0, stream>>>(x, bprev, b1, b2, blob, outp);
}